// Round 13
// baseline (77.185 us; speedup 1.0000x reference)
//
#include <hip/hip_runtime.h>
#include <hip/hip_bf16.h>
#include <cmath>

// Problem constants (fixed by reference)
#define NPTS  4096
#define HW    16384       // 128*128
#define WIDTH 128
#define NVIEW 4
#define KTOP  5
#define CAP   320         // 3-bin window candidates (max expected ~200)

struct AllViews {
    float m[NVIEW][12];   // per view: row-major 3x3 then T
};

__device__ __forceinline__ float fast_sigmoid(float x) {
    // 1/(1+e^-x): v_exp-based fast exp + hw rcp (~1-2 ulp; threshold is 1.2e-2)
    return __builtin_amdgcn_rcpf(1.0f + __expf(-x));
}

// One block per (view, row, x-half): 64 pixels, 4 threads/pixel.
// 1024 blocks x 256 thr = 4 blocks/CU = 16 waves/CU. Single dispatch, no d_ws.
// Staging loads only pcd (12 float4/thread, all issued up-front); sigmoid and
// displace/init gathers happen ONLY for the ~1.6% of points passing the y-window.
__global__ __launch_bounds__(256, 4)
void raster_fused(const float* __restrict__ pcd,
                  const float* __restrict__ displace,
                  const float* __restrict__ init_colors,
                  float* __restrict__ out,
                  float* __restrict__ out_colors,
                  AllViews av) {
    __shared__ float4 buf[CAP];
    __shared__ int cnt;
    __shared__ float mzs[4][64][KTOP];   // stride-5 floats: conflict-free
    __shared__ float mas[4][64][KTOP];
    __shared__ float mcs[4][64][KTOP];

    const int bid  = blockIdx.x;
    const int v    = bid >> 8;
    const int rem  = bid & 255;
    const int y    = rem >> 1;          // pixel row
    const int h    = rem & 1;           // x-half
    const int tid  = threadIdx.x;
    const int wave = tid >> 6;
    const int lane = tid & 63;
    const float* M = av.m[v];

    if (tid == 0) cnt = 0;
    __syncthreads();

    // colors_ tail: 128 (v==0,h==0) blocks each write 32 colors (4096 total, once)
    if ((v == 0) & (h == 0) & (tid < 32)) {
        int n = (y << 5) + tid;
        out_colors[n] = fast_sigmoid(init_colors[n] + displace[n]);
    }

    const float4* __restrict__ pcd4 = (const float4*)pcd;   // 3072 float4

    // 3-bin window [y-1, y+1] as float bounds on py: (1-py)*64 in [y-1, y+2)
    const float yLoF = 1.0f - (float)(y + 2) * (1.0f / 64.0f);   // py >  yLoF
    const float yHiF = 1.0f - (float)(y - 1) * (1.0f / 64.0f);   // py <= yHiF

    // all 12 pcd loads issued up-front, independent (named scalars, no spill)
    const int t3 = 3 * tid;
    float4 Q0 = pcd4[t3 + 0],        Q1 = pcd4[t3 + 1],        Q2 = pcd4[t3 + 2];
    float4 Q3 = pcd4[768 + t3 + 0],  Q4 = pcd4[768 + t3 + 1],  Q5 = pcd4[768 + t3 + 2];
    float4 Q6 = pcd4[1536 + t3 + 0], Q7 = pcd4[1536 + t3 + 1], Q8 = pcd4[1536 + t3 + 2];
    float4 Q9 = pcd4[2304 + t3 + 0], QA = pcd4[2304 + t3 + 1], QB = pcd4[2304 + t3 + 2];

    #define PT(N, X0, X1, X2)                                                \
    {                                                                        \
        float x0 = (X0), x1 = (X1), x2 = (X2);                               \
        float py = fmaf(x0, M[3], fmaf(x1, M[4], fmaf(x2, M[5], M[10])));    \
        if ((py > yLoF) & (py <= yHiF)) {                                    \
            float px  = fmaf(x0, M[0], fmaf(x1, M[1], fmaf(x2, M[2], M[9]))); \
            float pvz = fmaf(x0, M[6], fmaf(x1, M[7], fmaf(x2, M[8], M[11]))); \
            float pz  = (pvz - 0.01f) * (1.0f / 99.99f);                     \
            float s   = fast_sigmoid(init_colors[(N)] + displace[(N)]);      \
            int pos = atomicAdd(&cnt, 1);                                    \
            if (pos < CAP) buf[pos] = make_float4(px, py, pz, s);            \
        }                                                                    \
    }

    {
        const int n0 = tid << 2;
        PT(n0 + 0,      Q0.x, Q0.y, Q0.z);
        PT(n0 + 1,      Q0.w, Q1.x, Q1.y);
        PT(n0 + 2,      Q1.z, Q1.w, Q2.x);
        PT(n0 + 3,      Q2.y, Q2.z, Q2.w);
        PT(n0 + 1024,   Q3.x, Q3.y, Q3.z);
        PT(n0 + 1025,   Q3.w, Q4.x, Q4.y);
        PT(n0 + 1026,   Q4.z, Q4.w, Q5.x);
        PT(n0 + 1027,   Q5.y, Q5.z, Q5.w);
        PT(n0 + 2048,   Q6.x, Q6.y, Q6.z);
        PT(n0 + 2049,   Q6.w, Q7.x, Q7.y);
        PT(n0 + 2050,   Q7.z, Q7.w, Q8.x);
        PT(n0 + 2051,   Q8.y, Q8.z, Q8.w);
        PT(n0 + 3072,   Q9.x, Q9.y, Q9.z);
        PT(n0 + 3073,   Q9.w, QA.x, QA.y);
        PT(n0 + 3074,   QA.z, QA.w, QB.x);
        PT(n0 + 3075,   QB.y, QB.z, QB.w);
    }
    #undef PT
    __syncthreads();

    const int m = min(cnt, CAP);

    const int xi = (h << 6) + lane;
    const float xf = 1.0f - (2.0f * (float)xi + 1.0f) * (1.0f / 128.0f);
    const float yf = 1.0f - (2.0f * (float)y + 1.0f) * (1.0f / 128.0f);

    const float R2f   = (float)(0.02 * 0.02);
    const float invR2 = 1.0f / R2f;

    #define INS(nz, na, nc)                                                 \
    {                                                                       \
        float _z = (nz), _a = (na), _c = (nc);                              \
        _Pragma("unroll")                                                   \
        for (int k = 0; k < KTOP; ++k) {                                    \
            bool sw = _z < zs[k];                                           \
            float oz = zs[k], oa = as_[k], oc = cs[k];                      \
            zs[k]  = sw ? _z : oz;                                          \
            as_[k] = sw ? _a : oa;                                          \
            cs[k]  = sw ? _c : oc;                                          \
            _z = sw ? oz : _z;                                              \
            _a = sw ? oa : _a;                                              \
            _c = sw ? oc : _c;                                              \
        }                                                                   \
    }

    // phase 1: each wave scans its interleaved quarter (broadcast LDS reads)
    float zs[KTOP], as_[KTOP], cs[KTOP];
    #pragma unroll
    for (int k = 0; k < KTOP; ++k) { zs[k] = 3.0e38f; as_[k] = 0.0f; cs[k] = 0.0f; }

    for (int j = wave; j < m; j += 4) {
        float4 pt = buf[j];
        float dx = pt.x - xf;
        float dy = pt.y - yf;
        float d2 = fmaf(dx, dx, dy * dy);
        if ((d2 < R2f) & (pt.z > 0.0f) & (pt.z < zs[KTOP - 1]))
            INS(pt.z, 1.0f - d2 * invR2, pt.w);
    }

    #pragma unroll
    for (int k = 0; k < KTOP; ++k) {
        mzs[wave][lane][k] = zs[k];
        mas[wave][lane][k] = as_[k];
        mcs[wave][lane][k] = cs[k];
    }
    __syncthreads();

    // phase 2: wave 0 merges the 4 per-pixel lists and composites
    if (wave == 0) {
        #pragma unroll
        for (int k = 0; k < KTOP; ++k) { zs[k] = 3.0e38f; as_[k] = 0.0f; cs[k] = 0.0f; }
        #pragma unroll
        for (int w = 0; w < 4; ++w) {
            #pragma unroll
            for (int k = 0; k < KTOP; ++k) {
                float nz = mzs[w][lane][k];
                if (nz < zs[KTOP - 1]) INS(nz, mas[w][lane][k], mcs[w][lane][k]);
            }
        }

        float t = 1.0f, pix = 0.0f;
        #pragma unroll
        for (int k = 0; k < KTOP; ++k) {
            pix += as_[k] * t * cs[k];
            t *= (1.0f - as_[k]);
        }

        const int p = v * HW + (y << 7) + xi;
        float* o = out + 3 * (size_t)p;
        o[0] = pix; o[1] = pix; o[2] = pix;
    }
    #undef INS
}

static void compute_views(AllViews* av) {
    const double dist = 1.5;
    const double elev = 15.0 * M_PI / 180.0;
    const double az_deg[NVIEW] = {0.0, 90.0, 180.0, 270.0};
    for (int v = 0; v < NVIEW; ++v) {
        double az = az_deg[v] * M_PI / 180.0;
        double C[3] = { dist * cos(elev) * sin(az),
                        dist * sin(elev),
                        dist * cos(elev) * cos(az) };
        double nC = sqrt(C[0]*C[0] + C[1]*C[1] + C[2]*C[2]);
        double z[3] = { -C[0]/nC, -C[1]/nC, -C[2]/nC };
        double up[3] = { 0.0, 1.0, 0.0 };
        double x[3] = { up[1]*z[2] - up[2]*z[1],
                        up[2]*z[0] - up[0]*z[2],
                        up[0]*z[1] - up[1]*z[0] };
        double nx = sqrt(x[0]*x[0] + x[1]*x[1] + x[2]*x[2]);
        x[0] /= nx; x[1] /= nx; x[2] /= nx;
        double y[3] = { z[1]*x[2] - z[2]*x[1],
                        z[2]*x[0] - z[0]*x[2],
                        z[0]*x[1] - z[1]*x[0] };
        double* axes[3] = { x, y, z };
        for (int i = 0; i < 3; ++i) {
            av->m[v][3*i + 0] = (float)axes[i][0];
            av->m[v][3*i + 1] = (float)axes[i][1];
            av->m[v][3*i + 2] = (float)axes[i][2];
            av->m[v][9 + i] = (float)(-(axes[i][0]*C[0] + axes[i][1]*C[1] + axes[i][2]*C[2]));
        }
    }
}

extern "C" void kernel_launch(void* const* d_in, const int* in_sizes, int n_in,
                              void* d_out, int out_size, void* d_ws, size_t ws_size,
                              hipStream_t stream) {
    const float* pcd         = (const float*)d_in[0];
    const float* displace    = (const float*)d_in[1];
    const float* init_colors = (const float*)d_in[2];
    float* out = (float*)d_out;
    float* out_colors = out + (size_t)NVIEW * HW * 3;

    AllViews av;
    compute_views(&av);

    raster_fused<<<NVIEW * 256, 256, 0, stream>>>(pcd, displace, init_colors,
                                                  out, out_colors, av);
}